// Round 1
// baseline (2024.113 us; speedup 1.0000x reference)
//
#include <hip/hip_runtime.h>

// Problem constants (match reference)
#define BB 256      // batch
#define VV 50257    // per-model vocab
#define UU 65536    // union vocab
#define MM 3        // models

// ---------------------------------------------------------------------------
// Kernel 1: per-(model,row) sum of exp(logits).  winv[m*B+b] = w_m / sum.
// Logits are N(0,1) => exp() never overflows; softmax is shift-invariant so
// skipping max-subtraction is exact math, and fp32 accumulation error
// (~1e-7 rel) is far below the 1.9e-5 abs threshold on ~1e-3 outputs.
// One block per (m,b): 768 blocks x 512 threads -> 24 waves/CU, streaming.
// ---------------------------------------------------------------------------
__global__ __launch_bounds__(512) void row_sums_kernel(
    const float* __restrict__ l0, const float* __restrict__ l1,
    const float* __restrict__ l2, const float* __restrict__ weights,
    float* __restrict__ winv)
{
    const int bx = blockIdx.x;            // [0, MM*BB)
    const int m  = bx >> 8;               // BB == 256
    const int b  = bx & 255;
    const float* lg  = (m == 0) ? l0 : (m == 1) ? l1 : l2;
    const float* row = lg + (size_t)b * VV;

    float partial = 0.0f;
    for (int i = threadIdx.x; i < VV; i += 512)
        partial += __expf(row[i]);

    // wave (64-lane) reduce
    #pragma unroll
    for (int off = 32; off > 0; off >>= 1)
        partial += __shfl_down(partial, off, 64);

    __shared__ float smem[8];
    const int lane = threadIdx.x & 63;
    const int wv   = threadIdx.x >> 6;
    if (lane == 0) smem[wv] = partial;
    __syncthreads();
    if (threadIdx.x == 0) {
        float tot = 0.0f;
        #pragma unroll
        for (int w = 0; w < 8; ++w) tot += smem[w];
        winv[bx] = weights[m] / tot;
    }
}

// ---------------------------------------------------------------------------
// Kernel 2: scatter.  grid = (B*V/256, M).  Thread id covers one (b,j) of
// model blockIdx.y.  Coalesced logits+map reads; atomicAdd into the 256KB
// output row window (random within the window -> L2 atomics).
// ---------------------------------------------------------------------------
__global__ __launch_bounds__(256) void scatter_kernel(
    const float* __restrict__ l0, const float* __restrict__ l1,
    const float* __restrict__ l2,
    const int* __restrict__ m0, const int* __restrict__ m1,
    const int* __restrict__ m2,
    const float* __restrict__ winv,       // [MM*BB]
    float* __restrict__ out)              // [BB, UU]
{
    const int m  = blockIdx.y;
    const float* lg  = (m == 0) ? l0 : (m == 1) ? l1 : l2;
    const int*   mp  = (m == 0) ? m0 : (m == 1) ? m1 : m2;

    const int id = blockIdx.x * 256 + threadIdx.x;   // < BB*VV = 12,865,792
    const int b  = id / VV;                          // magic-mul (const divisor)
    const int j  = id - b * VV;

    const float val = winv[m * BB + b] * __expf(lg[id]);
    const int   u   = mp[j];
    atomicAdd(out + ((size_t)b * UU + u), val);
}

// ---------------------------------------------------------------------------
extern "C" void kernel_launch(void* const* d_in, const int* in_sizes, int n_in,
                              void* d_out, int out_size, void* d_ws, size_t ws_size,
                              hipStream_t stream)
{
    const float* l0 = (const float*)d_in[0];
    const float* l1 = (const float*)d_in[1];
    const float* l2 = (const float*)d_in[2];
    const int*   m0 = (const int*)d_in[3];
    const int*   m1 = (const int*)d_in[4];
    const int*   m2 = (const int*)d_in[5];
    const float* w  = (const float*)d_in[6];
    float* out  = (float*)d_out;
    float* winv = (float*)d_ws;            // MM*BB floats of scratch

    // zero the union output (0xAA-poisoned before every call)
    hipMemsetAsync(d_out, 0, (size_t)out_size * sizeof(float), stream);

    row_sums_kernel<<<MM * BB, 512, 0, stream>>>(l0, l1, l2, w, winv);

    dim3 grid((BB * VV) / 256, MM);        // 50257 x 3 blocks
    scatter_kernel<<<grid, 256, 0, stream>>>(l0, l1, l2, m0, m1, m2, winv, out);
}

// Round 2
// 545.424 us; speedup vs baseline: 3.7111x; 3.7111x over previous
//
#include <hip/hip_runtime.h>

// Problem constants
#define BB 256      // batch
#define VV 50257    // per-model vocab
#define UU 65536    // union vocab
#define MM 3        // models
#define NBUCK 8     // union-vocab buckets
#define BSZ  8192   // UU / NBUCK  (32 KB fp32 in LDS)

// 4B-aligned float4: rows start at 4B-aligned offsets (V*4 = 201028 B), and
// gfx950 global_load_dwordx4 only needs dword alignment.
typedef float float4a __attribute__((ext_vector_type(4), aligned(4)));

// ---------------------------------------------------------------------------
// Workspace layout (bytes):
//   0     : winv   [3*256] float
//   3072  : cnt    [3][8]  int    (memset to 0 each call)
//   3200  : off    [3][9]  int
//   3456  : cursor [3][8]  int
//   3584  : sorted [3][50257] int (packed (u&8191)<<16 | j)
// total ~607 KB
// ---------------------------------------------------------------------------
#define WS_WINV   0
#define WS_CNT    3072
#define WS_OFF    3200
#define WS_CURSOR 3456
#define WS_SORTED 3584

// ---------------------------------------------------------------------------
// Kernel 1: winv[m*B+b] = w_m / sum_j exp(logits[m][b][j]).
// Logits ~ N(0,1): unshifted exp is exact-math-safe (softmax shift-invariant).
// float4 loads: 154 MB streaming.
// ---------------------------------------------------------------------------
__global__ __launch_bounds__(512) void row_sums_kernel(
    const float* __restrict__ l0, const float* __restrict__ l1,
    const float* __restrict__ l2, const float* __restrict__ weights,
    float* __restrict__ winv)
{
    const int bx = blockIdx.x;            // [0, MM*BB)
    const int m  = bx >> 8;
    const int b  = bx & 255;
    const float* lg  = (m == 0) ? l0 : (m == 1) ? l1 : l2;
    const float* row = lg + (size_t)b * VV;
    const float4a* rowv = (const float4a*)row;

    const int nv4 = VV / 4;               // 12564, tail element j=50256
    float partial = 0.0f;
    for (int i = threadIdx.x; i < nv4; i += 512) {
        float4a v = rowv[i];
        partial += __expf(v.x) + __expf(v.y) + __expf(v.z) + __expf(v.w);
    }
    if (threadIdx.x == 0) partial += __expf(row[VV - 1]);

    #pragma unroll
    for (int off = 32; off > 0; off >>= 1)
        partial += __shfl_down(partial, off, 64);

    __shared__ float smem[8];
    const int lane = threadIdx.x & 63;
    const int wv   = threadIdx.x >> 6;
    if (lane == 0) smem[wv] = partial;
    __syncthreads();
    if (threadIdx.x == 0) {
        float tot = 0.0f;
        #pragma unroll
        for (int w = 0; w < 8; ++w) tot += smem[w];
        winv[bx] = weights[m] / tot;
    }
}

// ---------------------------------------------------------------------------
// Kernel 2: per-(m,bucket) counts.  grid (197, 3) x 256.
// ---------------------------------------------------------------------------
__global__ __launch_bounds__(256) void bucket_count_kernel(
    const int* __restrict__ m0, const int* __restrict__ m1,
    const int* __restrict__ m2, int* __restrict__ cnt)
{
    const int m = blockIdx.y;
    const int* mp = (m == 0) ? m0 : (m == 1) ? m1 : m2;
    __shared__ int hist[NBUCK];
    if (threadIdx.x < NBUCK) hist[threadIdx.x] = 0;
    __syncthreads();
    const int j = blockIdx.x * 256 + threadIdx.x;
    if (j < VV) atomicAdd(&hist[mp[j] >> 13], 1);
    __syncthreads();
    if (threadIdx.x < NBUCK) atomicAdd(&cnt[m * NBUCK + threadIdx.x], hist[threadIdx.x]);
}

// ---------------------------------------------------------------------------
// Kernel 3: tiny exclusive prefix per model; init cursors.  1 thread.
// ---------------------------------------------------------------------------
__global__ void bucket_prefix_kernel(const int* __restrict__ cnt,
                                     int* __restrict__ off, int* __restrict__ cursor)
{
    for (int m = 0; m < MM; ++m) {
        int acc = 0;
        for (int k = 0; k < NBUCK; ++k) {
            off[m * (NBUCK + 1) + k] = acc;
            cursor[m * NBUCK + k]    = acc;
            acc += cnt[m * NBUCK + k];
        }
        off[m * (NBUCK + 1) + NBUCK] = acc;   // == VV
    }
}

// ---------------------------------------------------------------------------
// Kernel 4: scatter j into bucket-sorted order (ascending-ish j per bucket).
// Wave-aggregated cursor atomics: 8 atomics/wave instead of 64.
// ---------------------------------------------------------------------------
__global__ __launch_bounds__(256) void bucket_scatter_kernel(
    const int* __restrict__ m0, const int* __restrict__ m1,
    const int* __restrict__ m2, int* __restrict__ cursor,
    int* __restrict__ sorted)
{
    const int m = blockIdx.y;
    const int* mp = (m == 0) ? m0 : (m == 1) ? m1 : m2;
    int* srt = sorted + (size_t)m * VV;

    const int j = blockIdx.x * 256 + threadIdx.x;
    int u = 0, bucket = NBUCK;            // NBUCK = inactive
    if (j < VV) { u = mp[j]; bucket = u >> 13; }

    const int lane = threadIdx.x & 63;
    const unsigned long long lt = (1ull << lane) - 1ull;

    #pragma unroll
    for (int k = 0; k < NBUCK; ++k) {
        unsigned long long mask = __ballot(bucket == k);
        if (mask) {
            int leader = __ffsll((long long)mask) - 1;
            int base = 0;
            if (lane == leader)
                base = atomicAdd(&cursor[m * NBUCK + k], __popcll(mask));
            base = __shfl(base, leader, 64);
            if (bucket == k) {
                int pos = base + __popcll(mask & lt);
                srt[pos] = ((u & (BSZ - 1)) << 16) | j;   // j < 2^16
            }
        }
    }
}

// ---------------------------------------------------------------------------
// Kernel 5: accumulate.  grid (NBUCK, BB).  32 KB LDS private accumulator,
// LDS float atomics, one coalesced 32 KB store.  Covers every output element
// exactly once -> no global memset needed.
// ---------------------------------------------------------------------------
__global__ __launch_bounds__(512) void accumulate_kernel(
    const float* __restrict__ l0, const float* __restrict__ l1,
    const float* __restrict__ l2,
    const int* __restrict__ sorted, const int* __restrict__ off,
    const float* __restrict__ winv, float* __restrict__ out)
{
    const int k = blockIdx.x;             // bucket
    const int b = blockIdx.y;             // row

    __shared__ float acc[BSZ];
    for (int i = threadIdx.x; i < BSZ; i += 512) acc[i] = 0.0f;
    __syncthreads();

    #pragma unroll
    for (int m = 0; m < MM; ++m) {
        const float* lg = (m == 0) ? l0 : (m == 1) ? l1 : l2;
        const float* row = lg + (size_t)b * VV;
        const int* srt = sorted + (size_t)m * VV;
        const float wv = winv[m * BB + b];
        const int s = off[m * (NBUCK + 1) + k];
        const int e = off[m * (NBUCK + 1) + k + 1];
        for (int i = s + threadIdx.x; i < e; i += 512) {
            const int pack = srt[i];
            const int j    = pack & 0xFFFF;
            const int ul   = pack >> 16;
            atomicAdd(&acc[ul], wv * __expf(row[j]));
        }
    }
    __syncthreads();

    float* orow = out + (size_t)b * UU + (size_t)k * BSZ;
    for (int i = threadIdx.x; i < BSZ; i += 512) orow[i] = acc[i];
}

// ---------------------------------------------------------------------------
extern "C" void kernel_launch(void* const* d_in, const int* in_sizes, int n_in,
                              void* d_out, int out_size, void* d_ws, size_t ws_size,
                              hipStream_t stream)
{
    const float* l0 = (const float*)d_in[0];
    const float* l1 = (const float*)d_in[1];
    const float* l2 = (const float*)d_in[2];
    const int*   m0 = (const int*)d_in[3];
    const int*   m1 = (const int*)d_in[4];
    const int*   m2 = (const int*)d_in[5];
    const float* w  = (const float*)d_in[6];
    float* out = (float*)d_out;

    char* ws = (char*)d_ws;
    float* winv   = (float*)(ws + WS_WINV);
    int*   cnt    = (int*)  (ws + WS_CNT);
    int*   off    = (int*)  (ws + WS_OFF);
    int*   cursor = (int*)  (ws + WS_CURSOR);
    int*   sorted = (int*)  (ws + WS_SORTED);

    // zero the 24 bucket counters (ws is 0xAA-poisoned each call)
    hipMemsetAsync(cnt, 0, MM * NBUCK * sizeof(int), stream);

    row_sums_kernel<<<MM * BB, 512, 0, stream>>>(l0, l1, l2, w, winv);

    dim3 gmap((VV + 255) / 256, MM);
    bucket_count_kernel<<<gmap, 256, 0, stream>>>(m0, m1, m2, cnt);
    bucket_prefix_kernel<<<1, 1, 0, stream>>>(cnt, off, cursor);
    bucket_scatter_kernel<<<gmap, 256, 0, stream>>>(m0, m1, m2, cursor, sorted);

    dim3 gacc(NBUCK, BB);
    accumulate_kernel<<<gacc, 512, 0, stream>>>(l0, l1, l2, sorted, off, winv, out);
}

// Round 3
// 339.074 us; speedup vs baseline: 5.9695x; 1.6086x over previous
//
#include <hip/hip_runtime.h>

// Problem constants
#define BB 256      // batch
#define VV 50257    // per-model vocab
#define UU 65536    // union vocab
#define MM 3        // models
#define NT 1024     // u-tiles (UU / 64)

typedef float float4a __attribute__((ext_vector_type(4), aligned(4)));

// ---------------------------------------------------------------------------
// FAST-PATH workspace layout (bytes):
//   0      : winv   [3*256] float
//   3072   : hist   [1024]  int   (memset 0 each call)
//   7168   : off    [1025]  int
//   11296  : cursor [1024]  int
//   15392  : sorted [150771] int  (packed (j<<8)|(m<<6)|(u&63))
//   618496 : ET     [3][50257][256] fp16  (77,194,752 B)
// total 77,813,248 B
// ---------------------------------------------------------------------------
#define WS_WINV   0
#define WS_HIST   3072
#define WS_OFF    7168
#define WS_CURSOR 11296
#define WS_SORTED 15392
#define WS_ET     618496
#define WS_NEED   77813248ull

// ---------------------------------------------------------------------------
// winv[m*B+b] = w_m / sum_j exp(logits[m][b][j]).  Logits ~ N(0,1): unshifted
// exp is exact-math-safe (softmax shift-invariance).
// ---------------------------------------------------------------------------
__global__ __launch_bounds__(512) void row_sums_kernel(
    const float* __restrict__ l0, const float* __restrict__ l1,
    const float* __restrict__ l2, const float* __restrict__ weights,
    float* __restrict__ winv)
{
    const int bx = blockIdx.x;            // [0, MM*BB)
    const int m  = bx >> 8;
    const int b  = bx & 255;
    const float* lg  = (m == 0) ? l0 : (m == 1) ? l1 : l2;
    const float* row = lg + (size_t)b * VV;
    const float4a* rowv = (const float4a*)row;

    const int nv4 = VV / 4;               // 12564, tail element j=50256
    float partial = 0.0f;
    for (int i = threadIdx.x; i < nv4; i += 512) {
        float4a v = rowv[i];
        partial += __expf(v.x) + __expf(v.y) + __expf(v.z) + __expf(v.w);
    }
    if (threadIdx.x == 0) partial += __expf(row[VV - 1]);

    #pragma unroll
    for (int off = 32; off > 0; off >>= 1)
        partial += __shfl_down(partial, off, 64);

    __shared__ float smem[8];
    const int lane = threadIdx.x & 63;
    const int wv   = threadIdx.x >> 6;
    if (lane == 0) smem[wv] = partial;
    __syncthreads();
    if (threadIdx.x == 0) {
        float tot = 0.0f;
        #pragma unroll
        for (int w = 0; w < 8; ++w) tot += smem[w];
        winv[bx] = weights[m] / tot;
    }
}

// ---------------------------------------------------------------------------
// u-tile histogram over all 3 maps.  64 blocks x 1024, LDS-aggregated.
// ---------------------------------------------------------------------------
__global__ __launch_bounds__(1024) void hist_count_kernel(
    const int* __restrict__ m0, const int* __restrict__ m1,
    const int* __restrict__ m2, int* __restrict__ hist)
{
    __shared__ int h[NT];
    for (int i = threadIdx.x; i < NT; i += 1024) h[i] = 0;
    __syncthreads();
    const int total = MM * VV;
    for (int idx = blockIdx.x * 1024 + threadIdx.x; idx < total;
         idx += gridDim.x * 1024) {
        const int m = idx / VV;           // const divisor -> magic mul
        const int j = idx - m * VV;
        const int* mp = (m == 0) ? m0 : (m == 1) ? m1 : m2;
        atomicAdd(&h[mp[j] >> 6], 1);
    }
    __syncthreads();
    for (int i = threadIdx.x; i < NT; i += 1024) atomicAdd(&hist[i], h[i]);
}

// ---------------------------------------------------------------------------
// Single-block exclusive scan over 1024 bins (Hillis-Steele in LDS).
// ---------------------------------------------------------------------------
__global__ __launch_bounds__(1024) void prefix_kernel(
    const int* __restrict__ hist, int* __restrict__ off, int* __restrict__ cursor)
{
    __shared__ int s[NT];
    const int t = threadIdx.x;
    const int mine = hist[t];
    s[t] = mine;
    __syncthreads();
    for (int d = 1; d < NT; d <<= 1) {
        int v = (t >= d) ? s[t - d] : 0;
        __syncthreads();
        s[t] += v;
        __syncthreads();
    }
    const int excl = s[t] - mine;
    off[t] = excl;
    cursor[t] = excl;
    if (t == NT - 1) off[NT] = s[t];
}

// ---------------------------------------------------------------------------
// Scatter (m,j,u) entries into u-tile-sorted order.
// ---------------------------------------------------------------------------
__global__ __launch_bounds__(256) void sort_kernel(
    const int* __restrict__ m0, const int* __restrict__ m1,
    const int* __restrict__ m2, int* __restrict__ cursor,
    int* __restrict__ sorted)
{
    const int total = MM * VV;
    for (int idx = blockIdx.x * 256 + threadIdx.x; idx < total;
         idx += gridDim.x * 256) {
        const int m = idx / VV;
        const int j = idx - m * VV;
        const int* mp = (m == 0) ? m0 : (m == 1) ? m1 : m2;
        const int u = mp[j];
        const int pos = atomicAdd(&cursor[u >> 6], 1);
        sorted[pos] = (j << 8) | (m << 6) | (u & 63);
    }
}

// ---------------------------------------------------------------------------
// Tiled transpose + exp: ET[m][j][b] = (fp16) exp(logits[m][b][j]).
// 64x64 tile through LDS; both global sides coalesced.
// ---------------------------------------------------------------------------
__global__ __launch_bounds__(256) void transpose_exp_kernel(
    const float* __restrict__ l0, const float* __restrict__ l1,
    const float* __restrict__ l2, _Float16* __restrict__ ET)
{
    const int m  = blockIdx.z;
    const float* lg = (m == 0) ? l0 : (m == 1) ? l1 : l2;
    const int j0 = blockIdx.x * 64;
    const int b0 = blockIdx.y * 64;
    __shared__ float tile[64][65];
    const int lane = threadIdx.x & 63;
    const int sub  = threadIdx.x >> 6;    // wave id 0..3

    const int j = j0 + lane;
    if (j < VV) {
        #pragma unroll
        for (int rr = 0; rr < 16; ++rr) {
            const int b = b0 + rr * 4 + sub;
            tile[lane][rr * 4 + sub] = __expf(lg[(size_t)b * VV + j]);
        }
    }
    __syncthreads();
    #pragma unroll
    for (int rr = 0; rr < 16; ++rr) {
        const int jj = rr * 4 + sub;
        const int jw = j0 + jj;
        if (jw < VV)
            ET[((size_t)m * VV + jw) * BB + b0 + lane] = (_Float16)tile[jj][lane];
    }
}

// ---------------------------------------------------------------------------
// Accumulate: block = one 64-wide u-tile, thread t = batch row b.
// Every ET element read exactly once, coalesced.  64 KB LDS accumulator with
// XOR bank swizzle; no atomics (thread t owns column b=t).  Full coverage ->
// no output memset.
// ---------------------------------------------------------------------------
__global__ __launch_bounds__(256) void accumulate_kernel(
    const _Float16* __restrict__ ET, const int* __restrict__ sorted,
    const int* __restrict__ off, const float* __restrict__ winv,
    float* __restrict__ out)
{
    const int k = blockIdx.x;             // u-tile
    const int t = threadIdx.x;            // b

    __shared__ float acc[64 * 256];
    for (int i = t; i < 64 * 256; i += 256) acc[i] = 0.0f;
    const float w0 = winv[0 * BB + t];
    const float w1 = winv[1 * BB + t];
    const float w2 = winv[2 * BB + t];
    __syncthreads();

    const int s = off[k], e = off[k + 1];
    #pragma unroll 4
    for (int i = s; i < e; ++i) {
        const int pack = sorted[i];       // block-uniform -> scalar load
        const int ul = pack & 63;
        const int m  = (pack >> 6) & 3;
        const int j  = pack >> 8;
        const float ev = (float)ET[((size_t)m * VV + j) * BB + t];
        const float w  = (m == 0) ? w0 : (m == 1) ? w1 : w2;
        acc[ul * 256 + (t ^ (ul & 31))] += w * ev;   // XOR swizzle, conflict-free
    }
    __syncthreads();

    const int u0 = k * 64;
    const int lane = t & 63, sub = t >> 6;
    #pragma unroll 4
    for (int c = 0; c < 64; ++c) {
        const int b = sub + c * 4;
        out[(size_t)b * UU + u0 + lane] = acc[lane * 256 + (b ^ (lane & 31))];
    }
}

// ===========================================================================
// FALLBACK (proven round-2 path) — used only if ws_size < WS_NEED.
// ===========================================================================
#define FB_NBUCK 8
#define FB_BSZ   8192

__global__ __launch_bounds__(256) void fb_count_kernel(
    const int* __restrict__ m0, const int* __restrict__ m1,
    const int* __restrict__ m2, int* __restrict__ cnt)
{
    const int m = blockIdx.y;
    const int* mp = (m == 0) ? m0 : (m == 1) ? m1 : m2;
    __shared__ int hist[FB_NBUCK];
    if (threadIdx.x < FB_NBUCK) hist[threadIdx.x] = 0;
    __syncthreads();
    const int j = blockIdx.x * 256 + threadIdx.x;
    if (j < VV) atomicAdd(&hist[mp[j] >> 13], 1);
    __syncthreads();
    if (threadIdx.x < FB_NBUCK)
        atomicAdd(&cnt[m * FB_NBUCK + threadIdx.x], hist[threadIdx.x]);
}

__global__ void fb_prefix_kernel(const int* __restrict__ cnt,
                                 int* __restrict__ off, int* __restrict__ cursor)
{
    for (int m = 0; m < MM; ++m) {
        int acc = 0;
        for (int k = 0; k < FB_NBUCK; ++k) {
            off[m * (FB_NBUCK + 1) + k] = acc;
            cursor[m * FB_NBUCK + k]    = acc;
            acc += cnt[m * FB_NBUCK + k];
        }
        off[m * (FB_NBUCK + 1) + FB_NBUCK] = acc;
    }
}

__global__ __launch_bounds__(256) void fb_scatter_kernel(
    const int* __restrict__ m0, const int* __restrict__ m1,
    const int* __restrict__ m2, int* __restrict__ cursor,
    int* __restrict__ sorted)
{
    const int m = blockIdx.y;
    const int* mp = (m == 0) ? m0 : (m == 1) ? m1 : m2;
    int* srt = sorted + (size_t)m * VV;
    const int j = blockIdx.x * 256 + threadIdx.x;
    int u = 0, bucket = FB_NBUCK;
    if (j < VV) { u = mp[j]; bucket = u >> 13; }
    const int lane = threadIdx.x & 63;
    const unsigned long long lt = (1ull << lane) - 1ull;
    #pragma unroll
    for (int k = 0; k < FB_NBUCK; ++k) {
        unsigned long long mask = __ballot(bucket == k);
        if (mask) {
            int leader = __ffsll((long long)mask) - 1;
            int base = 0;
            if (lane == leader)
                base = atomicAdd(&cursor[m * FB_NBUCK + k], __popcll(mask));
            base = __shfl(base, leader, 64);
            if (bucket == k) {
                int pos = base + __popcll(mask & lt);
                srt[pos] = ((u & (FB_BSZ - 1)) << 16) | j;
            }
        }
    }
}

__global__ __launch_bounds__(512) void fb_accumulate_kernel(
    const float* __restrict__ l0, const float* __restrict__ l1,
    const float* __restrict__ l2,
    const int* __restrict__ sorted, const int* __restrict__ off,
    const float* __restrict__ winv, float* __restrict__ out)
{
    const int k = blockIdx.x;
    const int b = blockIdx.y;
    __shared__ float acc[FB_BSZ];
    for (int i = threadIdx.x; i < FB_BSZ; i += 512) acc[i] = 0.0f;
    __syncthreads();
    #pragma unroll
    for (int m = 0; m < MM; ++m) {
        const float* lg = (m == 0) ? l0 : (m == 1) ? l1 : l2;
        const float* row = lg + (size_t)b * VV;
        const int* srt = sorted + (size_t)m * VV;
        const float wv = winv[m * BB + b];
        const int s = off[m * (FB_NBUCK + 1) + k];
        const int e = off[m * (FB_NBUCK + 1) + k + 1];
        for (int i = s + threadIdx.x; i < e; i += 512) {
            const int pack = srt[i];
            atomicAdd(&acc[pack >> 16], wv * __expf(row[pack & 0xFFFF]));
        }
    }
    __syncthreads();
    float* orow = out + (size_t)b * UU + (size_t)k * FB_BSZ;
    for (int i = threadIdx.x; i < FB_BSZ; i += 512) orow[i] = acc[i];
}

// ---------------------------------------------------------------------------
extern "C" void kernel_launch(void* const* d_in, const int* in_sizes, int n_in,
                              void* d_out, int out_size, void* d_ws, size_t ws_size,
                              hipStream_t stream)
{
    const float* l0 = (const float*)d_in[0];
    const float* l1 = (const float*)d_in[1];
    const float* l2 = (const float*)d_in[2];
    const int*   m0 = (const int*)d_in[3];
    const int*   m1 = (const int*)d_in[4];
    const int*   m2 = (const int*)d_in[5];
    const float* w  = (const float*)d_in[6];
    float* out = (float*)d_out;
    char* ws = (char*)d_ws;

    if (ws_size >= WS_NEED) {
        float*    winv   = (float*)   (ws + WS_WINV);
        int*      hist   = (int*)     (ws + WS_HIST);
        int*      off    = (int*)     (ws + WS_OFF);
        int*      cursor = (int*)     (ws + WS_CURSOR);
        int*      sorted = (int*)     (ws + WS_SORTED);
        _Float16* ET     = (_Float16*)(ws + WS_ET);

        hipMemsetAsync(hist, 0, NT * sizeof(int), stream);

        row_sums_kernel<<<MM * BB, 512, 0, stream>>>(l0, l1, l2, w, winv);
        hist_count_kernel<<<64, 1024, 0, stream>>>(m0, m1, m2, hist);
        prefix_kernel<<<1, 1024, 0, stream>>>(hist, off, cursor);
        sort_kernel<<<256, 256, 0, stream>>>(m0, m1, m2, cursor, sorted);

        dim3 gtr((VV + 63) / 64, BB / 64, MM);      // (786, 4, 3)
        transpose_exp_kernel<<<gtr, 256, 0, stream>>>(l0, l1, l2, ET);

        accumulate_kernel<<<NT, 256, 0, stream>>>(ET, sorted, off, winv, out);
    } else {
        // round-2 fallback layout
        float* winv   = (float*)(ws + 0);
        int*   cnt    = (int*)  (ws + 3072);
        int*   off    = (int*)  (ws + 3200);
        int*   cursor = (int*)  (ws + 3456);
        int*   sorted = (int*)  (ws + 3584);

        hipMemsetAsync(cnt, 0, MM * FB_NBUCK * sizeof(int), stream);
        row_sums_kernel<<<MM * BB, 512, 0, stream>>>(l0, l1, l2, w, winv);
        dim3 gmap((VV + 255) / 256, MM);
        fb_count_kernel<<<gmap, 256, 0, stream>>>(m0, m1, m2, cnt);
        fb_prefix_kernel<<<1, 1, 0, stream>>>(cnt, off, cursor);
        fb_scatter_kernel<<<gmap, 256, 0, stream>>>(m0, m1, m2, cursor, sorted);
        dim3 gacc(FB_NBUCK, BB);
        fb_accumulate_kernel<<<gacc, 512, 0, stream>>>(l0, l1, l2, sorted, off, winv, out);
    }
}